// Round 8
// baseline (209.858 us; speedup 1.0000x reference)
//
#include <hip/hip_runtime.h>
#include <hip/hip_bf16.h>
#include <stdint.h>

// RhymeLoss: mean over b in [0,4096), pairs i<j in [0,32) of
//   same(i,j) ? 1 - cos(u_i,u_j) : relu(cos(u_i,u_j) - 0.5)
//
// R8: CONTIGUOUS loads + high TLP, simultaneously (never combined before).
// Evidence table R1-R7: every fast kernel on this chip (fill 7 TB/s, copy
// 6.3, m146 4.9) uses single-segment contiguous wave-loads; every gather-
// shaped kernel of ours sits at 1.6-1.9 TB/s regardless of ILP (R2/R3),
// waves/CU (R6/R7), or DMA (R4). Hypothesis: per-CU miss tracking is
// segment-granular -> 16-segment fragment gathers cap in-flight at ~2 KB/CU.
//
// Structure: 2048 persistent blocks x 256 threads, 2 batches each.
//  - Cooperative staging: thread t loads 8 float4 at flat offsets
//    r*4KiB + 16*t (block-contiguous rounds -> single-segment wave-loads),
//    converts fp32->bf16 in-register, ds_writes to padded [32][264] layout
//    (per-lane LDS writes CAN use padding, unlike global_load_lds).
//  - K-split gram: wave wv computes partial gram over K in [wv*64,+64) via
//    ds_read_b128 fragments + 6 MFMA (A-frag == B-frag for a gram).
//  - Partials combine in s_acc OVERLAYED on s_stage (barrier-separated) ->
//    LDS ~17 KB -> 6-8 blocks/CU = 24-32 waves/CU.
//  - Wave 0: norms from gram diagonal, loss epilogue, one atomicAdd/batch.
//  - Batch 2's global loads are issued during batch 1's compute.

typedef short bf16x8 __attribute__((ext_vector_type(8)));   // 8 bf16 (4 VGPRs)
typedef short bf16x4 __attribute__((ext_vector_type(4)));   // 4 bf16 (2 VGPRs)
typedef float f32x4  __attribute__((ext_vector_type(4)));

#define MARGIN 0.5f
#define EPS_NORM 1e-8f
#define NPAIR_INV (1.0f / 2031616.0f)   // 1 / (4096 * 496)
#define ROW_S 264                        // shorts per staged row (256 + 8 pad)
#define NBLK  2048                       // persistent grid; batches b, b+2048

// fp32 -> bf16 round-to-nearest-even (inputs are finite, no NaN handling)
static __device__ __forceinline__ short f2bf(float f) {
    unsigned u = __float_as_uint(f);
    u += 0x7fffu + ((u >> 16) & 1u);
    return (short)(u >> 16);
}

__global__ __launch_bounds__(256) void rhyme_loss_kernel(
    const float* __restrict__ emb,   // [4096][32][256] fp32
    const int*   __restrict__ sch,   // [4096][32] int32
    float*       __restrict__ out)   // [1] fp32 (pre-zeroed)
{
    // s_stage (32*264 shorts = 16,896 B) overlays s_acc (3*3*64*16 = 9,216 B).
    __shared__ f32x4 s_mem[1056];                  // 16,896 B, 16B-aligned
    short* s_stage = (short*)s_mem;                // [32][ROW_S] bf16
    f32x4 (*s_acc)[3][64] = (f32x4 (*)[3][64])s_mem; // [wv-1][tile][lane]
    __shared__ float s_diag[32];
    __shared__ float s_inv[32];
    __shared__ int   s_sch2[2][32];

    const int t    = threadIdx.x;
    const int wv   = t >> 6;            // wave 0..3
    const int lane = t & 63;
    const int q    = lane >> 4;         // quad 0..3
    const int c    = lane & 15;         // fragment row (= C col)

    // Scheme for both batches, coalesced.
    if (t < 64)
        s_sch2[t >> 5][t & 31] =
            sch[((size_t)blockIdx.x + (size_t)(t >> 5) * NBLK) * 32 + (t & 31)];

    // Prefetch batch 0: 8 single-segment wave-loads (flat round r covers a
    // contiguous 4 KiB of the batch; thread t takes bytes 16t..16t+16).
    const float* gb = emb + (size_t)blockIdx.x * 8192;
    float4 pf[8];
    #pragma unroll
    for (int r = 0; r < 8; ++r)
        pf[r] = *(const float4*)(gb + r * 1024 + 4 * t);

    for (int it = 0; it < 2; ++it) {
        // ---- Stage: convert + transpose into padded LDS ----
        // Flat float idx r*1024 + 4t -> row 4r+wv, col 4*lane.
        #pragma unroll
        for (int r = 0; r < 8; ++r) {
            bf16x4 h;
            h[0] = f2bf(pf[r].x); h[1] = f2bf(pf[r].y);
            h[2] = f2bf(pf[r].z); h[3] = f2bf(pf[r].w);
            *(bf16x4*)(&s_stage[(4 * r + wv) * ROW_S + 4 * lane]) = h;
        }

        // Issue next batch's loads now; they drain behind this iteration's
        // barriers + MFMA + epilogue.
        if (it == 0) {
            const float* gb1 = emb + ((size_t)blockIdx.x + NBLK) * 8192;
            #pragma unroll
            for (int r = 0; r < 8; ++r)
                pf[r] = *(const float4*)(gb1 + r * 1024 + 4 * t);
        }

        __syncthreads();   // B1: staging visible to all waves

        // ---- K-split partial gram: wave wv covers K in [wv*64, +64) ----
        f32x4 a00 = {0.f, 0.f, 0.f, 0.f};   // rows 0-15  x cols 0-15
        f32x4 a01 = {0.f, 0.f, 0.f, 0.f};   // rows 0-15  x cols 16-31
        f32x4 a11 = {0.f, 0.f, 0.f, 0.f};   // rows 16-31 x cols 16-31
        #pragma unroll
        for (int ch = 0; ch < 2; ++ch) {
            const short* p0 = s_stage + c * ROW_S + wv * 64 + ch * 32 + q * 8;
            const short* p1 = p0 + 16 * ROW_S;
            bf16x8 f0 = *(const bf16x8*)p0;   // ds_read_b128, 16B-aligned
            bf16x8 f1 = *(const bf16x8*)p1;
            a00 = __builtin_amdgcn_mfma_f32_16x16x32_bf16(f0, f0, a00, 0, 0, 0);
            a01 = __builtin_amdgcn_mfma_f32_16x16x32_bf16(f0, f1, a01, 0, 0, 0);
            a11 = __builtin_amdgcn_mfma_f32_16x16x32_bf16(f1, f1, a11, 0, 0, 0);
        }

        __syncthreads();   // B2: all fragment reads done before overlay write

        if (wv != 0) {
            s_acc[wv - 1][0][lane] = a00;
            s_acc[wv - 1][1][lane] = a01;
            s_acc[wv - 1][2][lane] = a11;
        }
        __syncthreads();   // B3: partials visible to wave 0

        if (wv == 0) {
            #pragma unroll
            for (int p = 0; p < 3; ++p) {
                a00 += s_acc[p][0][lane];
                a01 += s_acc[p][1][lane];
                a11 += s_acc[p][2][lane];
            }

            // C/D layout (m89): col = lane&15, row = (lane>>4)*4 + reg.
            // Diagonal: reg = c - 4q when in [0,4).
            const int dreg = c - 4 * q;
            if (dreg >= 0 && dreg < 4) {
                s_diag[c]      = a00[dreg];   // ||u_c||^2
                s_diag[16 + c] = a11[dreg];   // ||u_{16+c}||^2
            }
            __builtin_amdgcn_wave_barrier();  // wave-local LDS ordering (R7-proven)
            if (lane < 32)
                s_inv[lane] = 1.0f / fmaxf(sqrtf(s_diag[lane]), EPS_NORM);
            __builtin_amdgcn_wave_barrier();

            const float invj0 = s_inv[c];
            const float invj1 = s_inv[16 + c];
            const int   sj0   = s_sch2[it][c];
            const int   sj1   = s_sch2[it][16 + c];

            float sum = 0.0f;
            #pragma unroll
            for (int r = 0; r < 4; ++r) {
                const int   i0    = q * 4 + r;
                const float inv_i = s_inv[i0];
                const int   si    = s_sch2[it][i0];

                // tile 01: i = i0 (<16), j = 16+c -> always i<j
                {
                    float sim = a01[r] * inv_i * invj1;
                    sum += (si == sj1) ? (1.0f - sim) : fmaxf(sim - MARGIN, 0.0f);
                }
                if (i0 < c) {
                    // tile 00: i = i0, j = c
                    float sim = a00[r] * inv_i * invj0;
                    sum += (si == sj0) ? (1.0f - sim) : fmaxf(sim - MARGIN, 0.0f);
                    // tile 11: i = 16+i0, j = 16+c
                    float sim2 = a11[r] * s_inv[16 + i0] * invj1;
                    sum += (s_sch2[it][16 + i0] == sj1) ? (1.0f - sim2)
                                                        : fmaxf(sim2 - MARGIN, 0.0f);
                }
            }

            // wave-64 reduction
            #pragma unroll
            for (int off = 32; off > 0; off >>= 1)
                sum += __shfl_down(sum, off, 64);

            if (lane == 0)
                atomicAdd(out, sum * NPAIR_INV);
        }

        __syncthreads();   // B4: wave 0 done with overlay before re-staging
    }
}

extern "C" void kernel_launch(void* const* d_in, const int* in_sizes, int n_in,
                              void* d_out, int out_size, void* d_ws, size_t ws_size,
                              hipStream_t stream) {
    const float* emb = (const float*)d_in[0];
    const int*   sch = (const int*)d_in[1];
    float*       out = (float*)d_out;

    hipMemsetAsync(out, 0, sizeof(float), stream);   // d_out is poisoned 0xAA
    rhyme_loss_kernel<<<dim3(NBLK), dim3(256), 0, stream>>>(emb, sch, out);
}

// Round 9
// 188.996 us; speedup vs baseline: 1.1104x; 1.1104x over previous
//
#include <hip/hip_runtime.h>
#include <hip/hip_bf16.h>
#include <stdint.h>

// RhymeLoss: mean over b in [0,4096), pairs i<j in [0,32) of
//   same(i,j) ? 1 - cos(u_i,u_j) : relu(cos(u_i,u_j) - 0.5)
//
// R9: KILL THE SAME-ADDRESS ATOMIC. R1-R8 post-mortem: five structurally
// disjoint kernels (gather/ILP/DMA/staged/TLP) all plateau at ~70-100 us
// with every pipe idle. The one invariant: 4096 atomicAdds to ONE fp32
// address. Device-scope same-address atomics serialize at the memory-side
// coherence point; 4096 x ~50cyc ~= 85 us -- exactly the wall, and it
// explains why load-structure changes never moved the number and why the
// atomic-free harness fill streams at 7 TB/s in the same graph.
//
// Structure: kernel A = R7's 4-way-K-split gram (numerics identical,
// absmax was 0.0) but the per-batch sum goes to d_ws[blockIdx.x] (4096
// distinct dwords, no contention). Kernel B (1 block) reduces the 4096
// partials and writes out[0] = total * NPAIR_INV.

typedef short bf16x8 __attribute__((ext_vector_type(8)));   // 8 bf16 (4 VGPRs)
typedef float f32x4  __attribute__((ext_vector_type(4)));

#define MARGIN 0.5f
#define EPS_NORM 1e-8f
#define NPAIR_INV (1.0f / 2031616.0f)   // 1 / (4096 * 496)

// fp32 -> bf16 round-to-nearest-even (inputs are finite, no NaN handling)
static __device__ __forceinline__ short f2bf(float f) {
    unsigned u = __float_as_uint(f);
    u += 0x7fffu + ((u >> 16) & 1u);
    return (short)(u >> 16);
}

__global__ __launch_bounds__(256, 8) void rhyme_loss_kernel(
    const float* __restrict__ emb,   // [4096][32][256] fp32
    const int*   __restrict__ sch,   // [4096][32] int32
    float*       __restrict__ part)  // [4096] fp32 per-batch partial sums
{
    __shared__ f32x4 s_acc[3][3][64];   // 9,216 B: waves 1-3 partial accs
    __shared__ float s_diag[32];
    __shared__ float s_inv[32];
    __shared__ int   s_sch[32];

    const int t    = threadIdx.x;
    const int wv   = t >> 6;            // wave 0..3 = K-quarter
    const int lane = t & 63;
    const int b    = blockIdx.x;        // one batch per block

    const int q = lane >> 4;            // quad 0..3 -> k-offset q*8
    const int c = lane & 15;            // fragment row (= C col)

    if (t < 32)   // scheme, coalesced dwords
        s_sch[t] = sch[(size_t)b * 32 + t];

    // Lane's source rows: c and 16+c, K-quarter wv. The lane's 8 floats per
    // row-chunk are CONTIGUOUS: [wv*64 + kc + q*8, +8).
    const float* base0 = emb + (size_t)b * 8192 + (size_t)c * 256 + wv * 64 + q * 8;
    const float* base1 = base0 + 16 * 256;

    f32x4 acc00 = {0.f, 0.f, 0.f, 0.f};   // rows 0-15  x cols 0-15  (partial K)
    f32x4 acc01 = {0.f, 0.f, 0.f, 0.f};   // rows 0-15  x cols 16-31
    f32x4 acc11 = {0.f, 0.f, 0.f, 0.f};   // rows 16-31 x cols 16-31
    // (tile 10 is the i>j mirror of 01 -> never needed)

    #pragma unroll
    for (int kc = 0; kc < 64; kc += 32) {
        float4 a0 = *(const float4*)(base0 + kc);
        float4 a1 = *(const float4*)(base0 + kc + 4);
        float4 b0 = *(const float4*)(base1 + kc);
        float4 b1 = *(const float4*)(base1 + kc + 4);

        bf16x8 f0, f1;
        f0[0] = f2bf(a0.x); f0[1] = f2bf(a0.y); f0[2] = f2bf(a0.z); f0[3] = f2bf(a0.w);
        f0[4] = f2bf(a1.x); f0[5] = f2bf(a1.y); f0[6] = f2bf(a1.z); f0[7] = f2bf(a1.w);
        f1[0] = f2bf(b0.x); f1[1] = f2bf(b0.y); f1[2] = f2bf(b0.z); f1[3] = f2bf(b0.w);
        f1[4] = f2bf(b1.x); f1[5] = f2bf(b1.y); f1[6] = f2bf(b1.z); f1[7] = f2bf(b1.w);

        // A-frag and B-frag of a gram share the same per-lane data.
        acc00 = __builtin_amdgcn_mfma_f32_16x16x32_bf16(f0, f0, acc00, 0, 0, 0);
        acc01 = __builtin_amdgcn_mfma_f32_16x16x32_bf16(f0, f1, acc01, 0, 0, 0);
        acc11 = __builtin_amdgcn_mfma_f32_16x16x32_bf16(f1, f1, acc11, 0, 0, 0);
    }

    // ---- K-combine: waves 1-3 publish partials; wave 0 sums ----
    if (wv != 0) {
        s_acc[wv - 1][0][lane] = acc00;
        s_acc[wv - 1][1][lane] = acc01;
        s_acc[wv - 1][2][lane] = acc11;
    }
    __syncthreads();

    if (wv == 0) {
        #pragma unroll
        for (int p = 0; p < 3; ++p) {
            acc00 += s_acc[p][0][lane];
            acc01 += s_acc[p][1][lane];
            acc11 += s_acc[p][2][lane];
        }

        // C/D layout (m89-verified): col = lane&15, row = (lane>>4)*4 + reg.
        // Diagonal of tiles 00/11: row==col -> reg = c - 4*q when in [0,4).
        const int dreg = c - 4 * q;
        if (dreg >= 0 && dreg < 4) {
            s_diag[c]      = acc00[dreg];   // ||u_c||^2
            s_diag[16 + c] = acc11[dreg];   // ||u_{16+c}||^2
        }
        // Intra-wave producer->consumer through LDS (R7-proven pattern).
        __builtin_amdgcn_wave_barrier();
        if (lane < 32)
            s_inv[lane] = 1.0f / fmaxf(sqrtf(s_diag[lane]), EPS_NORM);
        __builtin_amdgcn_wave_barrier();

        const float invj0 = s_inv[c];
        const float invj1 = s_inv[16 + c];
        const int   sj0   = s_sch[c];
        const int   sj1   = s_sch[16 + c];

        float sum = 0.0f;
        #pragma unroll
        for (int r = 0; r < 4; ++r) {
            const int   i0    = q * 4 + r;
            const float inv_i = s_inv[i0];
            const int   si    = s_sch[i0];

            // tile 01: i = i0 (<16), j = 16+c  -> always i<j
            {
                float sim = acc01[r] * inv_i * invj1;
                sum += (si == sj1) ? (1.0f - sim) : fmaxf(sim - MARGIN, 0.0f);
            }
            if (i0 < c) {
                // tile 00: i = i0, j = c
                float sim = acc00[r] * inv_i * invj0;
                sum += (si == sj0) ? (1.0f - sim) : fmaxf(sim - MARGIN, 0.0f);
                // tile 11: i = 16+i0, j = 16+c
                float sim2 = acc11[r] * s_inv[16 + i0] * invj1;
                sum += (s_sch[16 + i0] == sj1) ? (1.0f - sim2)
                                               : fmaxf(sim2 - MARGIN, 0.0f);
            }
        }

        // wave-64 reduction
        #pragma unroll
        for (int off = 32; off > 0; off >>= 1)
            sum += __shfl_down(sum, off, 64);

        // Contention-free: one plain store per batch.
        if (lane == 0)
            part[b] = sum;
    }
}

__global__ __launch_bounds__(256) void reduce_kernel(
    const float* __restrict__ part,  // [4096]
    float*       __restrict__ out)   // [1]
{
    __shared__ float s[4];
    const int t = threadIdx.x;
    float sum = 0.0f;
    const float4* p4 = (const float4*)part;   // 1024 float4
    #pragma unroll
    for (int i = 0; i < 4; ++i) {
        float4 v = p4[t + 256 * i];
        sum += (v.x + v.y) + (v.z + v.w);
    }
    #pragma unroll
    for (int off = 32; off > 0; off >>= 1)
        sum += __shfl_down(sum, off, 64);
    if ((t & 63) == 0) s[t >> 6] = sum;
    __syncthreads();
    if (t == 0)
        out[0] = ((s[0] + s[1]) + (s[2] + s[3])) * NPAIR_INV;
}

extern "C" void kernel_launch(void* const* d_in, const int* in_sizes, int n_in,
                              void* d_out, int out_size, void* d_ws, size_t ws_size,
                              hipStream_t stream) {
    const float* emb  = (const float*)d_in[0];
    const int*   sch  = (const int*)d_in[1];
    float*       out  = (float*)d_out;
    float*       part = (float*)d_ws;    // 4096 floats = 16 KiB scratch

    rhyme_loss_kernel<<<dim3(4096), dim3(256), 0, stream>>>(emb, sch, part);
    reduce_kernel<<<dim3(1), dim3(256), 0, stream>>>(part, out);
}